// Round 1
// baseline (226.157 us; speedup 1.0000x reference)
//
#include <hip/hip_runtime.h>
#include <hip/hip_bf16.h>

#define B_  512
#define L_  100
#define D_  128
#define SP_ 136      // Pt ushort stride
#define SO_ 132      // Ot float stride (528 B rows: 16B-aligned, 2-way max bank alias)

typedef unsigned short ushort_t;
typedef __attribute__((ext_vector_type(8))) unsigned short us8;
typedef __attribute__((ext_vector_type(8))) __bf16 bf8;
typedef __attribute__((ext_vector_type(4))) float f4;
typedef __attribute__((ext_vector_type(4))) float f4v;
typedef __attribute__((ext_vector_type(4))) int i4v;
typedef __attribute__((ext_vector_type(4))) unsigned int ui4;

__device__ __forceinline__ float b2f(ushort_t u) {
  union { unsigned i; float f; } v; v.i = ((unsigned)u) << 16; return v.f;
}
__device__ __forceinline__ ushort_t f2b(float f) {
  unsigned u = __float_as_uint(f);
  u += 0x7fffu + ((u >> 16) & 1u);   // RNE
  return (ushort_t)(u >> 16);
}
__device__ __forceinline__ us8 pack8(const float* x) {
  union { __hip_bfloat162 h; unsigned u; } cv;
  ui4 pk;
#pragma unroll
  for (int t = 0; t < 4; ++t) {
    cv.h = __float22bfloat162_rn(make_float2(x[2 * t], x[2 * t + 1]));
    pk[t] = cv.u;
  }
  return __builtin_bit_cast(us8, pk);
}
// XOR-swizzled Hs index (16B chunks contiguous; chunk ^= row&15)
__device__ __forceinline__ int sw(int row, int col) {
  return row * 128 + ((((col >> 3) ^ row) & 15) << 3) + (col & 7);
}

// One block per batch, 448 threads = 7 waves; wave w owns M-tile w.
// smem pool carve (bytes):
//   [0,     32768)  Hs   128x128 bf16 swizzled (later: H^T; later: aliased by Ot)
//   [32768, 63232)  Pt   7 x 16 x SP_ bf16     (later: aliased by Ot)
//   [63232, 73232)  adjS 100x100 u8
//   [73232, 75280)  aVf  4x128 f32
// Ot (f32, stride SO_) aliases [0, 59136) after the PV-read barrier.
//
// E phase runs as TWO head-passes (heads {0,1} then {2,3}) so the live
// A-fragment set is Af2[2][4] = 32 VGPRs instead of 64: peak register
// demand ~90 < the 128-reg unified cap from __launch_bounds__(448,4).
// (Previous single-pass version demanded ~190 regs -> ~58 MB of scratch
// spill writes per dispatch, visible as WRITE_SIZE 84.7 MB vs 26.2 ideal.)
__global__ __launch_bounds__(448, 4)
void CombineGraph_fused(const int* __restrict__ inp, const int* __restrict__ adjG,
                        const float* __restrict__ embF,
                        const float* __restrict__ a0F, const float* __restrict__ a1F,
                        const float* __restrict__ a2F, const float* __restrict__ a3F,
                        float* __restrict__ outG) {
  __shared__ __align__(16) unsigned char smem[75280];
  ushort_t* Hs = (ushort_t*)smem;
  ushort_t* Pt = (ushort_t*)(smem + 32768);
  unsigned char* adjS = smem + 63232;
  float* aVf = (float*)(smem + 73232);

  const int b = blockIdx.x, tid = threadIdx.x;
  const int w = tid / 64, lane = tid & 63, c = lane & 15, q = lane >> 4;

  // ---- phase 0: stage a_k, gather H (f32 emb -> bf16, rows>=100 zero), adj ----
  for (int u = tid; u < 512; u += 448) {
    int k = u >> 7, d = u & 127;
    const float* ak = (k == 0) ? a0F : (k == 1) ? a1F : (k == 2) ? a2F : a3F;
    aVf[u] = ak[d];
  }
  for (int u = tid; u < 128 * 16; u += 448) {            // (row, 8-elem chunk)
    int r = u >> 4, ch = u & 15;
    us8 o = {0, 0, 0, 0, 0, 0, 0, 0};
    if (r < L_) {
      int idx = inp[b * L_ + r];
      const float* src = embF + ((size_t)idx << 7) + ch * 8;
      f4v v0 = *(const f4v*)src;
      f4v v1 = *(const f4v*)(src + 4);
      float x[8];
#pragma unroll
      for (int t = 0; t < 4; ++t) { x[t] = v0[t]; x[4 + t] = v1[t]; }
      o = pack8(x);
    }
    *(us8*)&Hs[sw(r, ch * 8)] = o;
  }
  for (int u = tid; u < 2500; u += 448) {                // adj: int4 -> packed uchar4
    i4v v = *(const i4v*)(adjG + (size_t)b * 10000 + u * 4);
    unsigned pk = (unsigned)(v[0] & 255) | ((unsigned)(v[1] & 255) << 8) |
                  ((unsigned)(v[2] & 255) << 16) | ((unsigned)(v[3] & 255) << 24);
    *(unsigned*)&adjS[u * 4] = pk;
  }
  __syncthreads();

  // ---- E over all 7 j-tiles, two head-passes; select+leaky -> lg ----
  const int mi = w;
  float lg[7][4];
#pragma unroll 1
  for (int p = 0; p < 2; ++p) {
    // A-side for this pass: h row (m = c of tile w) * a_{2p}, a_{2p+1}
    us8 Af2[2][4];
#pragma unroll
    for (int ks = 0; ks < 4; ++ks) {
      us8 hr = *(const us8*)&Hs[sw(mi * 16 + c, ks * 32 + q * 8)];
      float hfv[8];
#pragma unroll
      for (int jj = 0; jj < 8; ++jj) hfv[jj] = b2f(hr[jj]);
#pragma unroll
      for (int kk = 0; kk < 2; ++kk) {
        const float* ap = &aVf[(p * 2 + kk) * 128 + ks * 32 + q * 8];
        f4v av0 = *(const f4v*)ap;
        f4v av1 = *(const f4v*)(ap + 4);
        float pr[8];
#pragma unroll
        for (int t = 0; t < 4; ++t) { pr[t] = hfv[t] * av0[t]; pr[4 + t] = hfv[4 + t] * av1[t]; }
        Af2[kk][ks] = pack8(pr);
      }
    }
#pragma unroll
    for (int nt = 0; nt < 7; ++nt) {
      f4 e0 = {0, 0, 0, 0}, e1 = {0, 0, 0, 0};
#pragma unroll
      for (int ks = 0; ks < 4; ++ks) {
        bf8 bb = __builtin_bit_cast(bf8, *(const us8*)&Hs[sw(nt * 16 + c, ks * 32 + q * 8)]);
        e0 = __builtin_amdgcn_mfma_f32_16x16x32_bf16(__builtin_bit_cast(bf8, Af2[0][ks]), bb, e0, 0, 0, 0);
        e1 = __builtin_amdgcn_mfma_f32_16x16x32_bf16(__builtin_bit_cast(bf8, Af2[1][ks]), bb, e1, 0, 0, 0);
      }
      int j = nt * 16 + c;
#pragma unroll
      for (int r = 0; r < 4; ++r) {
        int i = mi * 16 + q * 4 + r;
        int t = adjS[(i < L_ ? i : L_ - 1) * 100 + (j < L_ ? j : L_ - 1)];
        t = (i < L_ && j < L_) ? t : 0;
        float e = (t == p * 2 + 1) ? e0[r] : e1[r];
        e = (e > 0.f) ? e : 0.2f * e;               // leaky_relu(0.2)
        if (p == 0) {
          lg[nt][r] = (t == 1 || t == 2) ? e : -9e15f;
        } else {
          if (t == 3 || t == 4) lg[nt][r] = e;
        }
      }
    }
  }

  // ---- in-register softmax (reduce over 16 c-lanes within q-group, + over nt) ----
  ushort_t* Pw = Pt + w * 16 * SP_;
#pragma unroll
  for (int r = 0; r < 4; ++r) {
    float m = lg[0][r];
#pragma unroll
    for (int nt = 1; nt < 7; ++nt) m = fmaxf(m, lg[nt][r]);
#pragma unroll
    for (int off = 1; off <= 8; off <<= 1) m = fmaxf(m, __shfl_xor(m, off, 64));
    float ex[7], s = 0.f;
#pragma unroll
    for (int nt = 0; nt < 7; ++nt) { ex[nt] = __expf(lg[nt][r] - m); s += ex[nt]; }
#pragma unroll
    for (int off = 1; off <= 8; off <<= 1) s += __shfl_xor(s, off, 64);
    float inv = 1.0f / s;
    int row = q * 4 + r;
#pragma unroll
    for (int nt = 0; nt < 7; ++nt) Pw[row * SP_ + nt * 16 + c] = f2b(ex[nt] * inv);
  }
#pragma unroll
  for (int t = 0; t < 4; ++t) Pw[c * SP_ + 112 + q * 4 + t] = 0;   // zero K-pad 112..127

  __syncthreads();   // all E reads of Hs done

  // ---- in-place transpose of Hs (disjoint pair swaps) ----
  for (int u = tid; u < 8192; u += 448) {
    int d0 = u >> 7, j0 = u & 127;
    bool up = (j0 > d0);
    int d = up ? d0 : 127 - d0;
    int j = up ? j0 : 127 - j0;
    int ia = sw(d, j), ib = sw(j, d);
    ushort_t va = Hs[ia], vb = Hs[ib];
    Hs[ia] = vb; Hs[ib] = va;
  }
  __syncthreads();   // Hs now holds H^T

  // ---- PV: accumulate all 8 n-tiles into registers ----
  us8 Pf[4];
#pragma unroll
  for (int ks = 0; ks < 4; ++ks)
    Pf[ks] = *(const us8*)&Pw[c * SP_ + ks * 32 + q * 8];
  f4 oc[8];
#pragma unroll
  for (int nt2 = 0; nt2 < 8; ++nt2) {
    f4 a = {0, 0, 0, 0};
#pragma unroll
    for (int ks = 0; ks < 4; ++ks) {
      bf8 ob = __builtin_bit_cast(bf8, *(const us8*)&Hs[sw(nt2 * 16 + c, ks * 32 + q * 8)]);
      a = __builtin_amdgcn_mfma_f32_16x16x32_bf16(__builtin_bit_cast(bf8, Pf[ks]), ob, a, 0, 0, 0);
    }
    oc[nt2] = a;
  }
  __syncthreads();   // all Hs/Pt reads complete block-wide; safe to alias

  // ---- stage to LDS row-major, then fully-coalesced dwordx4 stores ----
  float* Ot = (float*)smem;                    // wave w region: [w*16*SO_, ...)
#pragma unroll
  for (int nt2 = 0; nt2 < 8; ++nt2)
#pragma unroll
    for (int r = 0; r < 4; ++r)
      Ot[(w * 16 + q * 4 + r) * SO_ + nt2 * 16 + c] = oc[nt2][r];
  // same-wave LDS RAW: compiler inserts lgkmcnt; no barrier needed.
#pragma unroll
  for (int it = 0; it < 8; ++it) {
    int u = it * 64 + lane;                    // wave-local: 16 rows x 32 f4-chunks
    int row16 = u >> 5, col4 = u & 31;
    int i = w * 16 + row16;
    if (i < L_) {
      f4 vv = *(const f4*)&Ot[(w * 16 + row16) * SO_ + col4 * 4];
      *(f4*)&outG[((size_t)b * L_ + i) * D_ + col4 * 4] = vv;
    }
  }
}

extern "C" void kernel_launch(void* const* d_in, const int* in_sizes, int n_in,
                              void* d_out, int out_size, void* d_ws, size_t ws_size,
                              hipStream_t stream) {
  (void)d_ws; (void)ws_size; (void)out_size;
  const int* inp = nullptr; const int* adj = nullptr;
  const float* emb = nullptr; const float* aP[4] = {nullptr, nullptr, nullptr, nullptr};
  int na = 0;
  for (int i = 0; i < n_in; ++i) {
    int s = in_sizes[i];
    if (s == 25600000)            emb = (const float*)d_in[i];
    else if (s == 5120000)        adj = (const int*)d_in[i];
    else if (s == 128 && na < 4)  aP[na++] = (const float*)d_in[i];
    else if (s == 51200 && !inp)  inp = (const int*)d_in[i];
  }
  CombineGraph_fused<<<dim3(B_), dim3(448), 0, stream>>>(
      inp, adj, emb, aP[0], aP[1], aP[2], aP[3], (float*)d_out);
}

// Round 2
// 190.773 us; speedup vs baseline: 1.1855x; 1.1855x over previous
//
#include <hip/hip_runtime.h>
#include <hip/hip_bf16.h>

#define B_  512
#define L_  100
#define D_  128
#define SP_ 136      // Pt ushort stride
#define SO_ 132      // Ot float stride (528 B rows: 16B-aligned, 2-way max bank alias)

typedef unsigned short ushort_t;
typedef __attribute__((ext_vector_type(8))) unsigned short us8;
typedef __attribute__((ext_vector_type(8))) __bf16 bf8;
typedef __attribute__((ext_vector_type(4))) float f4;
typedef __attribute__((ext_vector_type(4))) float f4v;
typedef __attribute__((ext_vector_type(4))) int i4v;
typedef __attribute__((ext_vector_type(4))) unsigned int ui4;

__device__ __forceinline__ float b2f(ushort_t u) {
  union { unsigned i; float f; } v; v.i = ((unsigned)u) << 16; return v.f;
}
__device__ __forceinline__ ushort_t f2b(float f) {
  unsigned u = __float_as_uint(f);
  u += 0x7fffu + ((u >> 16) & 1u);   // RNE
  return (ushort_t)(u >> 16);
}
__device__ __forceinline__ us8 pack8(const float* x) {
  union { __hip_bfloat162 h; unsigned u; } cv;
  ui4 pk;
#pragma unroll
  for (int t = 0; t < 4; ++t) {
    cv.h = __float22bfloat162_rn(make_float2(x[2 * t], x[2 * t + 1]));
    pk[t] = cv.u;
  }
  return __builtin_bit_cast(us8, pk);
}
// XOR-swizzled Hs index (16B chunks contiguous; chunk ^= row&15)
__device__ __forceinline__ int sw(int row, int col) {
  return row * 128 + ((((col >> 3) ^ row) & 15) << 3) + (col & 7);
}

// One block per batch, 448 threads = 7 waves; wave w owns M-tile w.
// smem pool carve (bytes):
//   [0,     32768)  Hs   128x128 bf16 swizzled (later: H^T; later: aliased by Ot)
//   [32768, 63232)  Pt   7 x 16 x SP_ bf16     (later: aliased by Ot)
//   [63232, 73232)  adjS 100x100 u8
//   [73232, 75280)  aVf  4x128 f32
// Ot (f32, stride SO_) aliases [0, 59136) after the PV-read barrier.
//
// E phase: HEAD-OUTER, fully unrolled (4 passes). Per pass only Afk[4]
// (16 VGPRs) + one f4 accumulator are live; lg[7][4] is updated with an
// unconditional cndmask select. Peak reg demand ~90 < the 128 unified cap
// from __launch_bounds__(448,4). Previous versions kept all 4 heads' A
// fragments (64 VGPRs) live -> scratch spill (WRITE_SIZE 84.7 MB vs 26.2
// ideal in r0; 145 MB + L2-missing reloads in r1's unroll-1 variant).
__global__ __launch_bounds__(448, 4)
void CombineGraph_fused(const int* __restrict__ inp, const int* __restrict__ adjG,
                        const float* __restrict__ embF,
                        const float* __restrict__ a0F, const float* __restrict__ a1F,
                        const float* __restrict__ a2F, const float* __restrict__ a3F,
                        float* __restrict__ outG) {
  __shared__ __align__(16) unsigned char smem[75280];
  ushort_t* Hs = (ushort_t*)smem;
  ushort_t* Pt = (ushort_t*)(smem + 32768);
  unsigned char* adjS = smem + 63232;
  float* aVf = (float*)(smem + 73232);

  const int b = blockIdx.x, tid = threadIdx.x;
  const int w = tid / 64, lane = tid & 63, c = lane & 15, q = lane >> 4;

  // ---- phase 0: stage a_k, gather H (f32 emb -> bf16, rows>=100 zero), adj ----
  for (int u = tid; u < 512; u += 448) {
    int k = u >> 7, d = u & 127;
    const float* ak = (k == 0) ? a0F : (k == 1) ? a1F : (k == 2) ? a2F : a3F;
    aVf[u] = ak[d];
  }
  for (int u = tid; u < 128 * 16; u += 448) {            // (row, 8-elem chunk)
    int r = u >> 4, ch = u & 15;
    us8 o = {0, 0, 0, 0, 0, 0, 0, 0};
    if (r < L_) {
      int idx = inp[b * L_ + r];
      const float* src = embF + ((size_t)idx << 7) + ch * 8;
      f4v v0 = *(const f4v*)src;
      f4v v1 = *(const f4v*)(src + 4);
      float x[8];
#pragma unroll
      for (int t = 0; t < 4; ++t) { x[t] = v0[t]; x[4 + t] = v1[t]; }
      o = pack8(x);
    }
    *(us8*)&Hs[sw(r, ch * 8)] = o;
  }
  for (int u = tid; u < 2500; u += 448) {                // adj: int4 -> packed uchar4
    i4v v = *(const i4v*)(adjG + (size_t)b * 10000 + u * 4);
    unsigned pk = (unsigned)(v[0] & 255) | ((unsigned)(v[1] & 255) << 8) |
                  ((unsigned)(v[2] & 255) << 16) | ((unsigned)(v[3] & 255) << 24);
    *(unsigned*)&adjS[u * 4] = pk;
  }
  __syncthreads();

  const int mi = w;

  // ---- hoist adj edge types: 4 rows (q*4+r) x col (nt*16+c), packed per nt ----
  unsigned tpk[7];
#pragma unroll
  for (int nt = 0; nt < 7; ++nt) {
    int j = nt * 16 + c;
    int jc = (j < L_) ? j : L_ - 1;
    unsigned pk = 0;
#pragma unroll
    for (int r = 0; r < 4; ++r) {
      int i = mi * 16 + q * 4 + r;
      int t = adjS[(i < L_ ? i : L_ - 1) * 100 + jc];
      t = (i < L_ && j < L_) ? t : 0;
      pk |= ((unsigned)t) << (8 * r);
    }
    tpk[nt] = pk;
  }

  float lg[7][4];
#pragma unroll
  for (int nt = 0; nt < 7; ++nt)
#pragma unroll
    for (int r = 0; r < 4; ++r) lg[nt][r] = -9e15f;

  // ---- E phase: head-outer, 4 fully-unrolled passes ----
#pragma unroll
  for (int k = 0; k < 4; ++k) {
    // A-frag for head k: h row (tile w, row c) ⊙ a_k  (pass-local, 16 VGPRs)
    us8 Afk[4];
#pragma unroll
    for (int ks = 0; ks < 4; ++ks) {
      us8 hr = *(const us8*)&Hs[sw(mi * 16 + c, ks * 32 + q * 8)];
      const float* ap = &aVf[k * 128 + ks * 32 + q * 8];
      f4v av0 = *(const f4v*)ap;
      f4v av1 = *(const f4v*)(ap + 4);
      float pr[8];
#pragma unroll
      for (int t = 0; t < 4; ++t) {
        pr[t]     = b2f(hr[t])     * av0[t];
        pr[4 + t] = b2f(hr[4 + t]) * av1[t];
      }
      Afk[ks] = pack8(pr);
    }
#pragma unroll
    for (int nt = 0; nt < 7; ++nt) {
      f4 acc = {0, 0, 0, 0};
#pragma unroll
      for (int ks = 0; ks < 4; ++ks) {
        bf8 bb = __builtin_bit_cast(bf8, *(const us8*)&Hs[sw(nt * 16 + c, ks * 32 + q * 8)]);
        acc = __builtin_amdgcn_mfma_f32_16x16x32_bf16(__builtin_bit_cast(bf8, Afk[ks]), bb, acc, 0, 0, 0);
      }
#pragma unroll
      for (int r = 0; r < 4; ++r) {
        int t = (int)((tpk[nt] >> (8 * r)) & 255u);
        float e = acc[r];
        e = (e > 0.f) ? e : 0.2f * e;               // leaky_relu(0.2)
        lg[nt][r] = (t == k + 1) ? e : lg[nt][r];   // cndmask, no branch
      }
    }
    // fence: keep each head pass's Afk build local (prevent 4x hoisting -> 64 regs)
    __builtin_amdgcn_sched_barrier(0);
  }

  // ---- in-register softmax (reduce over 16 c-lanes within q-group, + over nt) ----
  ushort_t* Pw = Pt + w * 16 * SP_;
#pragma unroll
  for (int r = 0; r < 4; ++r) {
    float m = lg[0][r];
#pragma unroll
    for (int nt = 1; nt < 7; ++nt) m = fmaxf(m, lg[nt][r]);
#pragma unroll
    for (int off = 1; off <= 8; off <<= 1) m = fmaxf(m, __shfl_xor(m, off, 64));
    float ex[7], s = 0.f;
#pragma unroll
    for (int nt = 0; nt < 7; ++nt) { ex[nt] = __expf(lg[nt][r] - m); s += ex[nt]; }
#pragma unroll
    for (int off = 1; off <= 8; off <<= 1) s += __shfl_xor(s, off, 64);
    float inv = 1.0f / s;
    int row = q * 4 + r;
#pragma unroll
    for (int nt = 0; nt < 7; ++nt) Pw[row * SP_ + nt * 16 + c] = f2b(ex[nt] * inv);
  }
#pragma unroll
  for (int t = 0; t < 4; ++t) Pw[c * SP_ + 112 + q * 4 + t] = 0;   // zero K-pad 112..127

  __syncthreads();   // all E reads of Hs done

  // ---- in-place transpose of Hs (disjoint pair swaps) ----
  for (int u = tid; u < 8192; u += 448) {
    int d0 = u >> 7, j0 = u & 127;
    bool up = (j0 > d0);
    int d = up ? d0 : 127 - d0;
    int j = up ? j0 : 127 - j0;
    int ia = sw(d, j), ib = sw(j, d);
    ushort_t va = Hs[ia], vb = Hs[ib];
    Hs[ia] = vb; Hs[ib] = va;
  }
  __syncthreads();   // Hs now holds H^T

  // ---- PV: accumulate all 8 n-tiles into registers ----
  us8 Pf[4];
#pragma unroll
  for (int ks = 0; ks < 4; ++ks)
    Pf[ks] = *(const us8*)&Pw[c * SP_ + ks * 32 + q * 8];
  f4 oc[8];
#pragma unroll
  for (int nt2 = 0; nt2 < 8; ++nt2) {
    f4 a = {0, 0, 0, 0};
#pragma unroll
    for (int ks = 0; ks < 4; ++ks) {
      bf8 ob = __builtin_bit_cast(bf8, *(const us8*)&Hs[sw(nt2 * 16 + c, ks * 32 + q * 8)]);
      a = __builtin_amdgcn_mfma_f32_16x16x32_bf16(__builtin_bit_cast(bf8, Pf[ks]), ob, a, 0, 0, 0);
    }
    oc[nt2] = a;
  }
  __syncthreads();   // all Hs/Pt reads complete block-wide; safe to alias

  // ---- stage to LDS row-major, then fully-coalesced dwordx4 stores ----
  float* Ot = (float*)smem;                    // wave w region: [w*16*SO_, ...)
#pragma unroll
  for (int nt2 = 0; nt2 < 8; ++nt2)
#pragma unroll
    for (int r = 0; r < 4; ++r)
      Ot[(w * 16 + q * 4 + r) * SO_ + nt2 * 16 + c] = oc[nt2][r];
  // same-wave LDS RAW: compiler inserts lgkmcnt; no barrier needed.
#pragma unroll
  for (int it = 0; it < 8; ++it) {
    int u = it * 64 + lane;                    // wave-local: 16 rows x 32 f4-chunks
    int row16 = u >> 5, col4 = u & 31;
    int i = w * 16 + row16;
    if (i < L_) {
      f4 vv = *(const f4*)&Ot[(w * 16 + row16) * SO_ + col4 * 4];
      *(f4*)&outG[((size_t)b * L_ + i) * D_ + col4 * 4] = vv;
    }
  }
}

extern "C" void kernel_launch(void* const* d_in, const int* in_sizes, int n_in,
                              void* d_out, int out_size, void* d_ws, size_t ws_size,
                              hipStream_t stream) {
  (void)d_ws; (void)ws_size; (void)out_size;
  const int* inp = nullptr; const int* adj = nullptr;
  const float* emb = nullptr; const float* aP[4] = {nullptr, nullptr, nullptr, nullptr};
  int na = 0;
  for (int i = 0; i < n_in; ++i) {
    int s = in_sizes[i];
    if (s == 25600000)            emb = (const float*)d_in[i];
    else if (s == 5120000)        adj = (const int*)d_in[i];
    else if (s == 128 && na < 4)  aP[na++] = (const float*)d_in[i];
    else if (s == 51200 && !inp)  inp = (const int*)d_in[i];
  }
  CombineGraph_fused<<<dim3(B_), dim3(448), 0, stream>>>(
      inp, adj, emb, aP[0], aP[1], aP[2], aP[3], (float*)d_out);
}